// Round 18
// baseline (444.201 us; speedup 1.0000x reference)
//
#include <hip/hip_runtime.h>
#include <math.h>

#define VSZ   30522
#define DIM   768
#define KDELT 768
#define BOT   512
#define BATCH 256
#define MNEG  4096
#define EPSN  1e-6f
#define TEMPC 0.05f
#define INVT  20.0f
#define TKT   1024

typedef _Float16 f16;
typedef _Float16 f16x8 __attribute__((ext_vector_type(8)));
typedef _Float16 f16x2 __attribute__((ext_vector_type(2)));
typedef float    f32x4 __attribute__((ext_vector_type(4)));

static __device__ __forceinline__ float gelu_exact(float x){
    return 0.5f * x * (1.0f + erff(x * 0.70710678118654752440f));
}
static __device__ __forceinline__ float softplus_f(float x){
    return fmaxf(x, 0.0f) + log1pf(expf(-fabsf(x)));
}
static __device__ __forceinline__ f16x2 pkh(float a, float b){
    return __builtin_bit_cast(f16x2, __builtin_amdgcn_cvt_pkrtz(a, b));
}
// order-preserving map float -> uint (handles negatives)
static __device__ __forceinline__ unsigned int fkey(float f){
    const unsigned int u = __float_as_uint(f);
    return u ^ (((unsigned int)((int)u >> 31)) | 0x80000000u);
}

// ---------------------------------------------------------------------------
// fp32-in / fp16-MFMA GEMM, 128xBN tile (BN in {64,128}) + XCD swizzle.
// R17: swizzle cut GEMM1 fetch 154->92.6MB, dur 113->93us; residual profile
// (1.37 TB/s, VALU 7%, MFMA 6.5%, occ 20%) = latency-bound at 2 blocks/CU
// (grid 512 is the cap). R9/R15 ledger: 4 blocks/CU streams ~2x, but
// splitting M duplicates WEIGHT reads (3x fetch). This round splits N
// instead: BN=64 doubles only the A-panel re-reads (A is the small matrix,
// L2-resident via swizzle); weight traffic unchanged. GEMM1 grid 1024
// (4/CU), GEMM2 1912 (7.5/CU). Per-wave 64x32 (acc[4][2], -32 VGPR).
// ---------------------------------------------------------------------------
template<int BSRC, int NG, int EPI, int LDA, int LDB, int N, int K, int NSPLIT,
         int BN, int GX, int GY, int GZ>
__global__ __launch_bounds__(256, 2) void gemm32t(
    const float* __restrict__ A0, const float* __restrict__ A1,
    const float* __restrict__ B0, const float* __restrict__ B1,
    float* __restrict__ C0, float* __restrict__ C1,
    const float* __restrict__ bias0, const float* __restrict__ bias1)
{
    constexpr int MN = BATCH * N;
    constexpr int NFR = BN / 32;          // B fragments per wave (2 or 4)
    __shared__ f16 Al[128][40];
    __shared__ f16 Bl[BN][40];
    const int t  = threadIdx.x;

    // ---- XCD-aware bijective remap (hw dispatch slot -> work id) ----
    const int flat = blockIdx.x + GX * (blockIdx.y + GY * blockIdx.z);
    constexpr int NWG = GX * GY * GZ;
    constexpr int q8 = NWG / 8, r8 = NWG % 8;
    const int xcd = flat & 7;
    const int sub = flat >> 3;
    const int wg  = (xcd < r8) ? (xcd * (q8 + 1) + sub)
                               : (r8 * (q8 + 1) + (xcd - r8) * q8 + sub);
    const int bx = wg % GX;
    const int by = (wg / GX) % GY;
    const int bz = wg / (GX * GY);

    const int m0 = bx * 128;
    const int n0 = by * BN;
    const int br = bz / NSPLIT;
    const int s  = bz % NSPLIT;
    const float* __restrict__ A = br ? A1 : A0;
    const float* __restrict__ B = br ? B1 : B0;
    float* __restrict__ C       = br ? C1 : C0;
    const float* __restrict__ bias = br ? bias1 : bias0;

    constexpr int kchunk = ((K + NSPLIT * 32 - 1) / (NSPLIT * 32)) * 32;
    const int kb = s * kchunk;
    const int ke = min(K, kb + kchunk);

    const int ar4 = t >> 2;          // staging row 0..63 (two passes)
    const int kq  = (t & 3) * 8;     // k-octet base 0,8,16,24
    const int bn  = t & (BN - 1);    // B transpose staging n
    const int bk2 = (t / BN) * (32 * BN / 256);  // BN=128: 0/16; BN=64: 0/8/16/24

    const int lane = t & 63, w = t >> 6;
    const int wr = (w >> 1) * 64;
    const int wc = (w & 1) * (16 * NFR);
    const int fr = lane & 15, kg = (lane >> 4) * 8;

    f32x4 acc[4][NFR] = {};

    float4 ra[2][2];
    float  rb[16];
    float4 rb2[2][2];

    union U8 { f16x8 v; f16x2 h[4]; };
    constexpr int BKT = 32 * BN / 256;   // B k's per thread (16 or 8)

    auto loadA = [&](int k0c, int krem) {
        #pragma unroll
        for (int p = 0; p < 2; p++) {
            const float* ap = A + (size_t)(m0 + p * 64 + ar4) * LDA + k0c + kq;
            if (krem == 32) {
                ra[p][0] = *(const float4*)ap;
                ra[p][1] = *(const float4*)(ap + 4);
            } else {
                float tm[8];
                #pragma unroll
                for (int i = 0; i < 8; i++) tm[i] = (kq + i < krem) ? ap[i] : 0.f;
                ra[p][0] = make_float4(tm[0], tm[1], tm[2], tm[3]);
                ra[p][1] = make_float4(tm[4], tm[5], tm[6], tm[7]);
            }
        }
    };
    auto loadB = [&](int k0c, int krem) {
        if (BSRC == 0) {
            const bool nok = (!NG) || (n0 + bn < N);
            if (krem == 32) {
                #pragma unroll
                for (int p = 0; p < BKT; p++)
                    rb[p] = nok ? B[(size_t)(k0c + bk2 + p) * LDB + n0 + bn] : 0.f;
            } else {
                #pragma unroll
                for (int p = 0; p < BKT; p++) {
                    const int kk = bk2 + p;
                    rb[p] = (kk < krem && nok) ? B[(size_t)(k0c + kk) * LDB + n0 + bn] : 0.f;
                }
            }
        } else {
            #pragma unroll
            for (int p = 0; p < 2; p++) {
                const float* bp = B + (size_t)(n0 + p * 64 + ar4) * LDB + k0c + kq;
                if (krem == 32) {
                    rb2[p][0] = *(const float4*)bp;
                    rb2[p][1] = *(const float4*)(bp + 4);
                } else {
                    float tm[8];
                    #pragma unroll
                    for (int i = 0; i < 8; i++) tm[i] = (kq + i < krem) ? bp[i] : 0.f;
                    rb2[p][0] = make_float4(tm[0], tm[1], tm[2], tm[3]);
                    rb2[p][1] = make_float4(tm[4], tm[5], tm[6], tm[7]);
                }
            }
        }
    };
    auto storeA = [&]() {
        #pragma unroll
        for (int p = 0; p < 2; p++) {
            U8 u;
            u.h[0] = pkh(ra[p][0].x, ra[p][0].y);
            u.h[1] = pkh(ra[p][0].z, ra[p][0].w);
            u.h[2] = pkh(ra[p][1].x, ra[p][1].y);
            u.h[3] = pkh(ra[p][1].z, ra[p][1].w);
            *(f16x8*)&Al[p * 64 + ar4][kq] = u.v;
        }
    };
    auto storeB = [&]() {
        if (BSRC == 0) {
            U8 u0;
            u0.h[0] = pkh(rb[0], rb[1]);
            u0.h[1] = pkh(rb[2], rb[3]);
            u0.h[2] = pkh(rb[4], rb[5]);
            u0.h[3] = pkh(rb[6], rb[7]);
            *(f16x8*)&Bl[bn][bk2] = u0.v;
            if (BKT == 16) {
                U8 u1;
                u1.h[0] = pkh(rb[8],  rb[9]);
                u1.h[1] = pkh(rb[10], rb[11]);
                u1.h[2] = pkh(rb[12], rb[13]);
                u1.h[3] = pkh(rb[14], rb[15]);
                *(f16x8*)&Bl[bn][bk2 + 8] = u1.v;
            }
        } else {
            #pragma unroll
            for (int p = 0; p < 2; p++) {
                U8 u;
                u.h[0] = pkh(rb2[p][0].x, rb2[p][0].y);
                u.h[1] = pkh(rb2[p][0].z, rb2[p][0].w);
                u.h[2] = pkh(rb2[p][1].x, rb2[p][1].y);
                u.h[3] = pkh(rb2[p][1].z, rb2[p][1].w);
                *(f16x8*)&Bl[p * 64 + ar4][kq] = u.v;
            }
        }
    };

    int k0 = kb;
    {
        const int kr = min(32, ke - k0);
        loadA(k0, kr); loadB(k0, kr);
    }
    while (k0 < ke) {
        storeA(); storeB();
        __syncthreads();
        const int k1 = k0 + 32;
        if (k1 < ke) {                       // prefetch next tile into regs
            const int kr = min(32, ke - k1);
            loadA(k1, kr); loadB(k1, kr);
        }
        f16x8 af[4], bf[NFR];
        #pragma unroll
        for (int m = 0; m < 4; m++) af[m] = *(const f16x8*)&Al[wr + m * 16 + fr][kg];
        #pragma unroll
        for (int n = 0; n < NFR; n++) bf[n] = *(const f16x8*)&Bl[wc + n * 16 + fr][kg];
        #pragma unroll
        for (int m = 0; m < 4; m++)
            #pragma unroll
            for (int n = 0; n < NFR; n++)
                acc[m][n] = __builtin_amdgcn_mfma_f32_16x16x32_f16(af[m], bf[n], acc[m][n], 0, 0, 0);
        __syncthreads();
        k0 = k1;
    }

    float* Cp = (EPI == 0) ? (C + (size_t)s * MN) : C;
    #pragma unroll
    for (int m = 0; m < 4; m++) {
        #pragma unroll
        for (int n = 0; n < NFR; n++) {
            #pragma unroll
            for (int j = 0; j < 4; j++) {
                const int row = m0 + wr + m * 16 + (lane >> 4) * 4 + j;
                const int col = n0 + wc + n * 16 + fr;
                if (NG && col >= N) continue;
                if (EPI == 0) Cp[(size_t)row * N + col] = acc[m][n][j];
                else          Cp[(size_t)row * N + col] = acc[m][n][j] + bias[col];
            }
        }
    }
}

// dual-branch split-K reduce + bias + exact GELU
__global__ __launch_bounds__(256) void reduce_bias_gelu2(
    const float* __restrict__ P0, const float* __restrict__ P1,
    const float* __restrict__ bias0, const float* __restrict__ bias1,
    float* __restrict__ H0, float* __restrict__ H1,
    int MN, int N, int nsplit)
{
    const int idx = blockIdx.x * 256 + threadIdx.x;
    if (idx >= MN) return;
    const int n = idx % N;
    const float* P = blockIdx.y ? P1 : P0;
    const float* bias = blockIdx.y ? bias1 : bias0;
    float* H = blockIdx.y ? H1 : H0;
    float s = 0.f;
    for (int k = 0; k < nsplit; k++) s += P[(size_t)k * MN + idx];
    H[idx] = gelu_exact(s + bias[n]);
}

__global__ __launch_bounds__(256) void reduce_sum_parts(
    const float* __restrict__ P, float* __restrict__ Y, int MN, int nsplit)
{
    const int idx = blockIdx.x * 256 + threadIdx.x;
    if (idx >= MN) return;
    float s = 0.f;
    for (int k = 0; k < nsplit; k++) s += P[(size_t)k * MN + idx];
    Y[idx] = s;
}

// ---------------------------------------------------------------------------
// Exact per-row K-th-largest on RAW (signed) logits via order-preserving
// uint key (fkey) and 12/12/8-bit radix select.
// ---------------------------------------------------------------------------
__global__ __launch_bounds__(TKT) void topk_thresh2(
    const float* __restrict__ U1, const float* __restrict__ U2,
    float* __restrict__ tP, float* __restrict__ tM)
{
    __shared__ unsigned int hist[4096];
    __shared__ unsigned int scan[TKT];
    __shared__ unsigned int s_pref;
    __shared__ int s_rem;
    const int row = blockIdx.y, t = threadIdx.x;
    const float* u = (blockIdx.x ? U2 : U1) + (size_t)row * VSZ;
    float* tout = blockIdx.x ? tM : tP;

    unsigned int pref = 0;
    int remain = KDELT;

    #pragma unroll
    for (int p = 0; p < 3; p++) {
        for (int i = t; i < 4096; i += TKT) hist[i] = 0;
        __syncthreads();
        for (int j = t; j < VSZ / 2; j += TKT) {
            const float2 x = *(const float2*)(u + 2 * j);
            const unsigned int k0 = fkey(x.x);
            const unsigned int k1 = fkey(x.y);
            if (p == 0) {
                atomicAdd(&hist[k0 >> 20], 1u);
                atomicAdd(&hist[k1 >> 20], 1u);
            } else if (p == 1) {
                if ((k0 >> 20) == pref) atomicAdd(&hist[(k0 >> 8) & 0xFFFu], 1u);
                if ((k1 >> 20) == pref) atomicAdd(&hist[(k1 >> 8) & 0xFFFu], 1u);
            } else {
                if ((k0 >> 8) == pref) atomicAdd(&hist[k0 & 0xFFu], 1u);
                if ((k1 >> 8) == pref) atomicAdd(&hist[k1 & 0xFFu], 1u);
            }
        }
        __syncthreads();
        // suffix scan: thread t owns bins [4t, 4t+4)
        unsigned int loc = hist[4 * t] + hist[4 * t + 1] + hist[4 * t + 2] + hist[4 * t + 3];
        scan[t] = loc;
        __syncthreads();
        for (int o = 1; o < TKT; o <<= 1) {
            const unsigned int v = (t + o < TKT) ? scan[t + o] : 0u;
            __syncthreads();
            scan[t] += v;
            __syncthreads();
        }
        const unsigned int above = (t + 1 < TKT) ? scan[t + 1] : 0u;
        if (scan[t] >= (unsigned int)remain && above < (unsigned int)remain) {
            unsigned int cum = above;
            #pragma unroll
            for (int bi = 3; bi >= 0; bi--) {
                const int b = 4 * t + bi;
                cum += hist[b];
                if (cum >= (unsigned int)remain) {
                    s_pref = (unsigned int)b;
                    s_rem  = remain - (int)(cum - hist[b]);
                    break;
                }
            }
        }
        __syncthreads();
        if (p == 0)      pref = s_pref;
        else if (p == 1) pref = (pref << 12) | s_pref;
        else             pref = (pref << 8)  | s_pref;
        remain = s_rem;
        __syncthreads();
    }
    if (t == 0) {
        const unsigned int u2 = (pref & 0x80000000u) ? (pref ^ 0x80000000u) : ~pref;
        tout[row] = __uint_as_float(u2);
    }
}

// U1 := clip(sr + dsp,0) - dsm with dsp/dsm = softplus on selected elements.
__global__ __launch_bounds__(256) void build_sq(
    float* __restrict__ U1, const float* __restrict__ U2,
    const float* __restrict__ sr,
    const float* __restrict__ tp, const float* __restrict__ tm,
    float* __restrict__ sparse_p, float* __restrict__ sparse_m)
{
    __shared__ float red[256];
    const int row = blockIdx.x, t = threadIdx.x;
    const float thp = tp[row], thm = tm[row];
    float* u1 = U1 + (size_t)row * VSZ;
    const float* u2 = U2 + (size_t)row * VSZ;
    const float* s  = sr + (size_t)row * VSZ;
    float sp = 0.f, sm = 0.f;
    for (int j = t; j < VSZ / 2; j += 256) {
        const float2 up = *(const float2*)(u1 + 2 * j);
        const float2 um = *(const float2*)(u2 + 2 * j);
        const float2 ss = *(const float2*)(s  + 2 * j);
        const float dp0 = (up.x >= thp) ? softplus_f(up.x) : 0.f;
        const float dp1 = (up.y >= thp) ? softplus_f(up.y) : 0.f;
        const float dm0 = (um.x >= thm) ? softplus_f(um.x) : 0.f;
        const float dm1 = (um.y >= thm) ? softplus_f(um.y) : 0.f;
        sp += dp0 + dp1; sm += dm0 + dm1;
        float2 o;
        o.x = fmaxf(ss.x + dp0, 0.f) - dm0;
        o.y = fmaxf(ss.y + dp1, 0.f) - dm1;
        *(float2*)(u1 + 2 * j) = o;
    }
    red[t] = sp; __syncthreads();
    for (int o = 128; o > 0; o >>= 1) { if (t < o) red[t] += red[t + o]; __syncthreads(); }
    if (t == 0) sparse_p[row] = red[0];
    __syncthreads();
    red[t] = sm; __syncthreads();
    for (int o = 128; o > 0; o >>= 1) { if (t < o) red[t] += red[t + o]; __syncthreads(); }
    if (t == 0) sparse_m[row] = red[0];
}

__global__ __launch_bounds__(256) void rownorm(
    const float* __restrict__ X, float* __restrict__ Y, int dbl)
{
    __shared__ float red[256];
    const int row = blockIdx.x, t = threadIdx.x;
    const float* x = X + (size_t)row * DIM;
    float* y = Y + (size_t)row * DIM;
    float v0 = x[t], v1 = x[t + 256], v2 = x[t + 512];
    red[t] = v0 * v0 + v1 * v1 + v2 * v2; __syncthreads();
    for (int o = 128; o > 0; o >>= 1) { if (t < o) red[t] += red[t + o]; __syncthreads(); }
    const float nrm = sqrtf(red[0]) + EPSN;
    v0 /= nrm; v1 /= nrm; v2 /= nrm;
    if (dbl) {
        __syncthreads();
        red[t] = v0 * v0 + v1 * v1 + v2 * v2; __syncthreads();
        for (int o = 128; o > 0; o >>= 1) { if (t < o) red[t] += red[t + o]; __syncthreads(); }
        const float n2 = sqrtf(red[0]) + EPSN;
        v0 /= n2; v1 /= n2; v2 /= n2;
    }
    y[t] = v0; y[t + 256] = v1; y[t + 512] = v2;
}

__global__ __launch_bounds__(256) void pos_dot(
    const float* __restrict__ zq, const float* __restrict__ zp,
    float* __restrict__ posL)
{
    __shared__ float red[256];
    const int row = blockIdx.x, t = threadIdx.x;
    const float* a = zq + (size_t)row * DIM;
    const float* b = zp + (size_t)row * DIM;
    red[t] = a[t] * b[t] + a[t + 256] * b[t + 256] + a[t + 512] * b[t + 512];
    __syncthreads();
    for (int o = 128; o > 0; o >>= 1) { if (t < o) red[t] += red[t + o]; __syncthreads(); }
    if (t == 0) posL[row] = red[0] / TEMPC;
}

// NegL holds raw dot products; scale by 1/TEMP here.
__global__ __launch_bounds__(256) void lse_loss(
    const float* __restrict__ negL, const float* __restrict__ posL,
    float* __restrict__ rowL)
{
    __shared__ float red[256];
    const int row = blockIdx.x, t = threadIdx.x;
    const float* nl = negL + (size_t)row * MNEG;
    const float p = posL[row];
    float lmax = (t == 0) ? p : -INFINITY;
    for (int j = t; j < MNEG; j += 256) lmax = fmaxf(lmax, nl[j] * INVT);
    red[t] = lmax; __syncthreads();
    for (int o = 128; o > 0; o >>= 1) { if (t < o) red[t] = fmaxf(red[t], red[t + o]); __syncthreads(); }
    const float mx = red[0];
    __syncthreads();
    float lsum = (t == 0) ? expf(p - mx) : 0.f;
    for (int j = t; j < MNEG; j += 256) lsum += expf(nl[j] * INVT - mx);
    red[t] = lsum; __syncthreads();
    for (int o = 128; o > 0; o >>= 1) { if (t < o) red[t] += red[t + o]; __syncthreads(); }
    if (t == 0) rowL[row] = mx + logf(red[0]) - p;
}

__global__ __launch_bounds__(256) void rec_row(
    const float* __restrict__ zhat, const float* __restrict__ zrn,
    float* __restrict__ part)
{
    __shared__ float red[256];
    const int row = blockIdx.x, t = threadIdx.x;
    const float* a = zhat + (size_t)row * DIM;
    const float* b = zrn + (size_t)row * DIM;
    const float d0 = a[t] - b[t], d1 = a[t + 256] - b[t + 256], d2 = a[t + 512] - b[t + 512];
    red[t] = d0 * d0 + d1 * d1 + d2 * d2;
    __syncthreads();
    for (int o = 128; o > 0; o >>= 1) { if (t < o) red[t] += red[t + o]; __syncthreads(); }
    if (t == 0) part[row] = red[0];
}

__global__ __launch_bounds__(256) void final_combine(
    const float* __restrict__ rowL, const float* __restrict__ recP,
    const float* __restrict__ spP, const float* __restrict__ spM,
    float* __restrict__ out)
{
    __shared__ float red[256];
    const int t = threadIdx.x;
    red[t] = rowL[t]; __syncthreads();
    for (int o = 128; o > 0; o >>= 1) { if (t < o) red[t] += red[t + o]; __syncthreads(); }
    const float retr = red[0] / 256.0f;
    __syncthreads();
    red[t] = recP[t]; __syncthreads();
    for (int o = 128; o > 0; o >>= 1) { if (t < o) red[t] += red[t + o]; __syncthreads(); }
    const float rec = red[0] / (float)(BATCH * DIM);
    __syncthreads();
    red[t] = spP[t] + spM[t]; __syncthreads();
    for (int o = 128; o > 0; o >>= 1) { if (t < o) red[t] += red[t + o]; __syncthreads(); }
    const float sparse = red[0] / 256.0f;
    if (t == 0) out[0] = retr + 1.0f * rec + 1e-4f * sparse;
}

extern "C" void kernel_launch(void* const* d_in, const int* in_sizes, int n_in,
                              void* d_out, int out_size, void* d_ws, size_t ws_size,
                              hipStream_t stream)
{
    const float* ht   = (const float*)d_in[0];
    const float* sr   = (const float*)d_in[1];
    const float* zpos = (const float*)d_in[2];
    const float* zneg = (const float*)d_in[3];
    const float* zr   = (const float*)d_in[4];
    const float* W1p  = (const float*)d_in[5];
    const float* b1p  = (const float*)d_in[6];
    const float* W2p  = (const float*)d_in[7];
    const float* b2p  = (const float*)d_in[8];
    const float* W1m  = (const float*)d_in[9];
    const float* b1m  = (const float*)d_in[10];
    const float* W2m  = (const float*)d_in[11];
    const float* b2m  = (const float*)d_in[12];
    const float* Wdec = (const float*)d_in[13];
    float* out = (float*)d_out;

    // workspace layout (bytes) — R8 layout
    char* ws = (char*)d_ws;
    float* U1   = (float*)(ws + 0);            // 31,254,528 (u_p raw -> sq)
    float* U2   = (float*)(ws + 31254528);     // 31,254,528 (u_m raw; dead after build_sq ->
                                               //   reused as decode branch-m partials)
    float* P    = (float*)(ws + 62509056);     // 33,554,432 partial arena (serial reuse)
    float* P1g  = (float*)(ws + 62509056 + 16777216);  // gemm1 branch-m partials
    float* Hp   = (float*)(ws + 96063488);     //      524,288
    float* Hm   = (float*)(ws + 96587776);     //      524,288
    float* Y1   = (float*)(ws + 97112064);     //      786,432
    float* Y2   = (float*)(ws + 97898496);     //      786,432
    float* Zn   = (float*)(ws + 98684928);     //   12,582,912
    float* Zp   = (float*)(ws + 111267840);    //      786,432
    float* Zrn  = (float*)(ws + 112054272);    //      786,432
    float* NegL = (float*)(ws + 112840704);    //    4,194,304
    float* tP   = (float*)(ws + 117035008);    // small vectors (256 floats each)
    float* tM   = tP + 256;
    float* spP  = tP + 512;
    float* spM  = tP + 768;
    float* posL = tP + 1024;
    float* rowL = tP + 1280;
    float* recP = tP + 1536;
    (void)in_sizes; (void)n_in; (void)out_size; (void)ws_size;

    const dim3 blk(256);

    // ---- GEMM1 dual (ht@W1p | ht@W1m), BN=64, split-K 32, grid 1024 (4/CU)
    gemm32t<0,0,0, VSZ, BOT, BOT, VSZ, 32, 64, 2,8,64><<<dim3(2,8,64), blk, 0, stream>>>(
        ht, ht, W1p, W1m, P, P1g, nullptr, nullptr);
    reduce_bias_gelu2<<<dim3(512,2), blk, 0, stream>>>(
        P, P1g, b1p, b1m, Hp, Hm, BATCH*BOT, BOT, 32);

    // ---- GEMM2 dual (Hp@W2p | Hm@W2m), BN=64, raw epilogue, grid 1912 (7.5/CU)
    gemm32t<0,1,1, BOT, VSZ, VSZ, BOT, 1, 64, 2,478,2><<<dim3(2,478,2), blk, 0, stream>>>(
        Hp, Hm, W2p, W2m, U1, U2, b2p, b2m);

    // ---- exact top-K thresholds on raw logits (both branches, one launch)
    topk_thresh2<<<dim3(2,256), dim3(TKT), 0, stream>>>(U1, U2, tP, tM);
    build_sq<<<dim3(256), blk, 0, stream>>>(U1, U2, sr, tP, tM, spP, spM);

    // ---- decode dual (sq@Wdec | sr@Wdec), BN=128, split-K 32, grid 768
    gemm32t<0,0,0, VSZ, DIM, DIM, VSZ, 32, 128, 2,6,64><<<dim3(2,6,64), blk, 0, stream>>>(
        U1, sr, Wdec, Wdec, P, U2, nullptr, nullptr);
    reduce_sum_parts<<<dim3(768), blk, 0, stream>>>(P,  Y1, BATCH*DIM, 32);
    reduce_sum_parts<<<dim3(768), blk, 0, stream>>>(U2, Y2, BATCH*DIM, 32);

    // ---- normalizations
    rownorm<<<dim3(256),  blk, 0, stream>>>(Y1, Y1, 1);   // zq (double norm)
    rownorm<<<dim3(256),  blk, 0, stream>>>(Y2, Y2, 0);   // zhat_r
    rownorm<<<dim3(4096), blk, 0, stream>>>(zneg, Zn, 0);
    rownorm<<<dim3(256),  blk, 0, stream>>>(zpos, Zp, 0);
    rownorm<<<dim3(256),  blk, 0, stream>>>(zr,   Zrn, 0);

    // ---- retrieval loss
    pos_dot<<<dim3(256), blk, 0, stream>>>(Y1, Zp, posL);
    gemm32t<1,0,0, DIM, DIM, MNEG, DIM, 4, 128, 2,32,4><<<dim3(2,32,4), blk, 0, stream>>>(
        Y1, Y1, Zn, Zn, P, P, nullptr, nullptr);
    reduce_sum_parts<<<dim3(4096), blk, 0, stream>>>(P, NegL, BATCH*MNEG, 4);
    lse_loss<<<dim3(256), blk, 0, stream>>>(NegL, posL, rowL);

    // ---- reconstruction loss
    rec_row<<<dim3(256), blk, 0, stream>>>(Y2, Zrn, recP);

    // ---- combine
    final_combine<<<dim3(1), blk, 0, stream>>>(rowL, recP, spP, spM, out);
}

// Round 19
// 426.242 us; speedup vs baseline: 1.0421x; 1.0421x over previous
//
#include <hip/hip_runtime.h>
#include <math.h>

#define VSZ   30522
#define DIM   768
#define KDELT 768
#define BOT   512
#define BATCH 256
#define MNEG  4096
#define EPSN  1e-6f
#define TEMPC 0.05f
#define INVT  20.0f
#define TKT   1024

typedef _Float16 f16;
typedef _Float16 f16x8 __attribute__((ext_vector_type(8)));
typedef _Float16 f16x2 __attribute__((ext_vector_type(2)));
typedef float    f32x4 __attribute__((ext_vector_type(4)));

static __device__ __forceinline__ float gelu_exact(float x){
    return 0.5f * x * (1.0f + erff(x * 0.70710678118654752440f));
}
static __device__ __forceinline__ float softplus_f(float x){
    return fmaxf(x, 0.0f) + log1pf(expf(-fabsf(x)));
}
static __device__ __forceinline__ f16x2 pkh(float a, float b){
    return __builtin_bit_cast(f16x2, __builtin_amdgcn_cvt_pkrtz(a, b));
}
// order-preserving map float -> uint (handles negatives)
static __device__ __forceinline__ unsigned int fkey(float f){
    const unsigned int u = __float_as_uint(f);
    return u ^ (((unsigned int)((int)u >> 31)) | 0x80000000u);
}

// ---------------------------------------------------------------------------
// fp32-in / fp16-MFMA GEMM, 128x128 tile + XCD swizzle (R17 kernel, best
// 410.7us). R18's BN=64 experiment REGRESSED (occ 35% but BW 1.05 TB/s —
// halved per-block MFMA/barrier + codegen shift); BN=128 restored.
// R18 change is launch-config only: GEMM1 NSPLIT 32->64 (grid 1024, 4/CU)
// WITH the swizzle — R15 ran split-64 pre-swizzle and lost to traffic
// (337MB); swizzled, each z-slice's 8 blocks share A 0.49MB + W 0.98MB
// (L2-fit) so FETCH should hold ~95MB while doubling resident blocks.
// ---------------------------------------------------------------------------
template<int BSRC, int NG, int EPI, int LDA, int LDB, int N, int K, int NSPLIT,
         int GX, int GY, int GZ>
__global__ __launch_bounds__(256, 2) void gemm32t(
    const float* __restrict__ A0, const float* __restrict__ A1,
    const float* __restrict__ B0, const float* __restrict__ B1,
    float* __restrict__ C0, float* __restrict__ C1,
    const float* __restrict__ bias0, const float* __restrict__ bias1)
{
    constexpr int MN = BATCH * N;
    __shared__ f16 Al[128][40];
    __shared__ f16 Bl[128][40];
    const int t  = threadIdx.x;

    // ---- XCD-aware bijective remap (hw dispatch slot -> work id) ----
    const int flat = blockIdx.x + GX * (blockIdx.y + GY * blockIdx.z);
    constexpr int NWG = GX * GY * GZ;
    constexpr int q8 = NWG / 8, r8 = NWG % 8;
    const int xcd = flat & 7;
    const int sub = flat >> 3;
    const int wg  = (xcd < r8) ? (xcd * (q8 + 1) + sub)
                               : (r8 * (q8 + 1) + (xcd - r8) * q8 + sub);
    const int bx = wg % GX;
    const int by = (wg / GX) % GY;
    const int bz = wg / (GX * GY);

    const int m0 = bx * 128;
    const int n0 = by * 128;
    const int br = bz / NSPLIT;
    const int s  = bz % NSPLIT;
    const float* __restrict__ A = br ? A1 : A0;
    const float* __restrict__ B = br ? B1 : B0;
    float* __restrict__ C       = br ? C1 : C0;
    const float* __restrict__ bias = br ? bias1 : bias0;

    constexpr int kchunk = ((K + NSPLIT * 32 - 1) / (NSPLIT * 32)) * 32;
    const int kb = s * kchunk;
    const int ke = min(K, kb + kchunk);

    const int ar4 = t >> 2;          // staging row 0..63 (two passes)
    const int kq  = (t & 3) * 8;     // k-octet base 0,8,16,24
    const int bn  = t & 127;         // B transpose staging n
    const int bk2 = (t >> 7) * 16;   // B staging k-half base 0/16

    const int lane = t & 63, w = t >> 6;
    const int wr = (w >> 1) * 64, wc = (w & 1) * 64;
    const int fr = lane & 15, kg = (lane >> 4) * 8;

    f32x4 acc[4][4] = {};

    float4 ra[2][2];
    float  rb[16];
    float4 rb2[2][2];

    union U8 { f16x8 v; f16x2 h[4]; };

    auto loadA = [&](int k0c, int krem) {
        #pragma unroll
        for (int p = 0; p < 2; p++) {
            const float* ap = A + (size_t)(m0 + p * 64 + ar4) * LDA + k0c + kq;
            if (krem == 32) {
                ra[p][0] = *(const float4*)ap;
                ra[p][1] = *(const float4*)(ap + 4);
            } else {
                float tm[8];
                #pragma unroll
                for (int i = 0; i < 8; i++) tm[i] = (kq + i < krem) ? ap[i] : 0.f;
                ra[p][0] = make_float4(tm[0], tm[1], tm[2], tm[3]);
                ra[p][1] = make_float4(tm[4], tm[5], tm[6], tm[7]);
            }
        }
    };
    auto loadB = [&](int k0c, int krem) {
        if (BSRC == 0) {
            const bool nok = (!NG) || (n0 + bn < N);
            if (krem == 32) {
                #pragma unroll
                for (int p = 0; p < 16; p++)
                    rb[p] = nok ? B[(size_t)(k0c + bk2 + p) * LDB + n0 + bn] : 0.f;
            } else {
                #pragma unroll
                for (int p = 0; p < 16; p++) {
                    const int kk = bk2 + p;
                    rb[p] = (kk < krem && nok) ? B[(size_t)(k0c + kk) * LDB + n0 + bn] : 0.f;
                }
            }
        } else {
            #pragma unroll
            for (int p = 0; p < 2; p++) {
                const float* bp = B + (size_t)(n0 + p * 64 + ar4) * LDB + k0c + kq;
                if (krem == 32) {
                    rb2[p][0] = *(const float4*)bp;
                    rb2[p][1] = *(const float4*)(bp + 4);
                } else {
                    float tm[8];
                    #pragma unroll
                    for (int i = 0; i < 8; i++) tm[i] = (kq + i < krem) ? bp[i] : 0.f;
                    rb2[p][0] = make_float4(tm[0], tm[1], tm[2], tm[3]);
                    rb2[p][1] = make_float4(tm[4], tm[5], tm[6], tm[7]);
                }
            }
        }
    };
    auto storeA = [&]() {
        #pragma unroll
        for (int p = 0; p < 2; p++) {
            U8 u;
            u.h[0] = pkh(ra[p][0].x, ra[p][0].y);
            u.h[1] = pkh(ra[p][0].z, ra[p][0].w);
            u.h[2] = pkh(ra[p][1].x, ra[p][1].y);
            u.h[3] = pkh(ra[p][1].z, ra[p][1].w);
            *(f16x8*)&Al[p * 64 + ar4][kq] = u.v;
        }
    };
    auto storeB = [&]() {
        if (BSRC == 0) {
            U8 u0, u1;
            u0.h[0] = pkh(rb[0],  rb[1]);
            u0.h[1] = pkh(rb[2],  rb[3]);
            u0.h[2] = pkh(rb[4],  rb[5]);
            u0.h[3] = pkh(rb[6],  rb[7]);
            u1.h[0] = pkh(rb[8],  rb[9]);
            u1.h[1] = pkh(rb[10], rb[11]);
            u1.h[2] = pkh(rb[12], rb[13]);
            u1.h[3] = pkh(rb[14], rb[15]);
            *(f16x8*)&Bl[bn][bk2]     = u0.v;
            *(f16x8*)&Bl[bn][bk2 + 8] = u1.v;
        } else {
            #pragma unroll
            for (int p = 0; p < 2; p++) {
                U8 u;
                u.h[0] = pkh(rb2[p][0].x, rb2[p][0].y);
                u.h[1] = pkh(rb2[p][0].z, rb2[p][0].w);
                u.h[2] = pkh(rb2[p][1].x, rb2[p][1].y);
                u.h[3] = pkh(rb2[p][1].z, rb2[p][1].w);
                *(f16x8*)&Bl[p * 64 + ar4][kq] = u.v;
            }
        }
    };

    int k0 = kb;
    {
        const int kr = min(32, ke - k0);
        loadA(k0, kr); loadB(k0, kr);
    }
    while (k0 < ke) {
        storeA(); storeB();
        __syncthreads();
        const int k1 = k0 + 32;
        if (k1 < ke) {                       // prefetch next tile into regs
            const int kr = min(32, ke - k1);
            loadA(k1, kr); loadB(k1, kr);
        }
        f16x8 af[4], bf[4];
        #pragma unroll
        for (int m = 0; m < 4; m++) af[m] = *(const f16x8*)&Al[wr + m * 16 + fr][kg];
        #pragma unroll
        for (int n = 0; n < 4; n++) bf[n] = *(const f16x8*)&Bl[wc + n * 16 + fr][kg];
        #pragma unroll
        for (int m = 0; m < 4; m++)
            #pragma unroll
            for (int n = 0; n < 4; n++)
                acc[m][n] = __builtin_amdgcn_mfma_f32_16x16x32_f16(af[m], bf[n], acc[m][n], 0, 0, 0);
        __syncthreads();
        k0 = k1;
    }

    float* Cp = (EPI == 0) ? (C + (size_t)s * MN) : C;
    #pragma unroll
    for (int m = 0; m < 4; m++) {
        #pragma unroll
        for (int n = 0; n < 4; n++) {
            #pragma unroll
            for (int j = 0; j < 4; j++) {
                const int row = m0 + wr + m * 16 + (lane >> 4) * 4 + j;
                const int col = n0 + wc + n * 16 + fr;
                if (NG && col >= N) continue;
                if (EPI == 0) Cp[(size_t)row * N + col] = acc[m][n][j];
                else          Cp[(size_t)row * N + col] = acc[m][n][j] + bias[col];
            }
        }
    }
}

// dual-branch split-K reduce + bias + exact GELU
__global__ __launch_bounds__(256) void reduce_bias_gelu2(
    const float* __restrict__ P0, const float* __restrict__ P1,
    const float* __restrict__ bias0, const float* __restrict__ bias1,
    float* __restrict__ H0, float* __restrict__ H1,
    int MN, int N, int nsplit)
{
    const int idx = blockIdx.x * 256 + threadIdx.x;
    if (idx >= MN) return;
    const int n = idx % N;
    const float* P = blockIdx.y ? P1 : P0;
    const float* bias = blockIdx.y ? bias1 : bias0;
    float* H = blockIdx.y ? H1 : H0;
    float s = 0.f;
    for (int k = 0; k < nsplit; k++) s += P[(size_t)k * MN + idx];
    H[idx] = gelu_exact(s + bias[n]);
}

__global__ __launch_bounds__(256) void reduce_sum_parts(
    const float* __restrict__ P, float* __restrict__ Y, int MN, int nsplit)
{
    const int idx = blockIdx.x * 256 + threadIdx.x;
    if (idx >= MN) return;
    float s = 0.f;
    for (int k = 0; k < nsplit; k++) s += P[(size_t)k * MN + idx];
    Y[idx] = s;
}

// ---------------------------------------------------------------------------
// Exact per-row K-th-largest on RAW (signed) logits via order-preserving
// uint key (fkey) and 12/12/8-bit radix select.
// ---------------------------------------------------------------------------
__global__ __launch_bounds__(TKT) void topk_thresh2(
    const float* __restrict__ U1, const float* __restrict__ U2,
    float* __restrict__ tP, float* __restrict__ tM)
{
    __shared__ unsigned int hist[4096];
    __shared__ unsigned int scan[TKT];
    __shared__ unsigned int s_pref;
    __shared__ int s_rem;
    const int row = blockIdx.y, t = threadIdx.x;
    const float* u = (blockIdx.x ? U2 : U1) + (size_t)row * VSZ;
    float* tout = blockIdx.x ? tM : tP;

    unsigned int pref = 0;
    int remain = KDELT;

    #pragma unroll
    for (int p = 0; p < 3; p++) {
        for (int i = t; i < 4096; i += TKT) hist[i] = 0;
        __syncthreads();
        for (int j = t; j < VSZ / 2; j += TKT) {
            const float2 x = *(const float2*)(u + 2 * j);
            const unsigned int k0 = fkey(x.x);
            const unsigned int k1 = fkey(x.y);
            if (p == 0) {
                atomicAdd(&hist[k0 >> 20], 1u);
                atomicAdd(&hist[k1 >> 20], 1u);
            } else if (p == 1) {
                if ((k0 >> 20) == pref) atomicAdd(&hist[(k0 >> 8) & 0xFFFu], 1u);
                if ((k1 >> 20) == pref) atomicAdd(&hist[(k1 >> 8) & 0xFFFu], 1u);
            } else {
                if ((k0 >> 8) == pref) atomicAdd(&hist[k0 & 0xFFu], 1u);
                if ((k1 >> 8) == pref) atomicAdd(&hist[k1 & 0xFFu], 1u);
            }
        }
        __syncthreads();
        // suffix scan: thread t owns bins [4t, 4t+4)
        unsigned int loc = hist[4 * t] + hist[4 * t + 1] + hist[4 * t + 2] + hist[4 * t + 3];
        scan[t] = loc;
        __syncthreads();
        for (int o = 1; o < TKT; o <<= 1) {
            const unsigned int v = (t + o < TKT) ? scan[t + o] : 0u;
            __syncthreads();
            scan[t] += v;
            __syncthreads();
        }
        const unsigned int above = (t + 1 < TKT) ? scan[t + 1] : 0u;
        if (scan[t] >= (unsigned int)remain && above < (unsigned int)remain) {
            unsigned int cum = above;
            #pragma unroll
            for (int bi = 3; bi >= 0; bi--) {
                const int b = 4 * t + bi;
                cum += hist[b];
                if (cum >= (unsigned int)remain) {
                    s_pref = (unsigned int)b;
                    s_rem  = remain - (int)(cum - hist[b]);
                    break;
                }
            }
        }
        __syncthreads();
        if (p == 0)      pref = s_pref;
        else if (p == 1) pref = (pref << 12) | s_pref;
        else             pref = (pref << 8)  | s_pref;
        remain = s_rem;
        __syncthreads();
    }
    if (t == 0) {
        const unsigned int u2 = (pref & 0x80000000u) ? (pref ^ 0x80000000u) : ~pref;
        tout[row] = __uint_as_float(u2);
    }
}

// U1 := clip(sr + dsp,0) - dsm with dsp/dsm = softplus on selected elements.
__global__ __launch_bounds__(256) void build_sq(
    float* __restrict__ U1, const float* __restrict__ U2,
    const float* __restrict__ sr,
    const float* __restrict__ tp, const float* __restrict__ tm,
    float* __restrict__ sparse_p, float* __restrict__ sparse_m)
{
    __shared__ float red[256];
    const int row = blockIdx.x, t = threadIdx.x;
    const float thp = tp[row], thm = tm[row];
    float* u1 = U1 + (size_t)row * VSZ;
    const float* u2 = U2 + (size_t)row * VSZ;
    const float* s  = sr + (size_t)row * VSZ;
    float sp = 0.f, sm = 0.f;
    for (int j = t; j < VSZ / 2; j += 256) {
        const float2 up = *(const float2*)(u1 + 2 * j);
        const float2 um = *(const float2*)(u2 + 2 * j);
        const float2 ss = *(const float2*)(s  + 2 * j);
        const float dp0 = (up.x >= thp) ? softplus_f(up.x) : 0.f;
        const float dp1 = (up.y >= thp) ? softplus_f(up.y) : 0.f;
        const float dm0 = (um.x >= thm) ? softplus_f(um.x) : 0.f;
        const float dm1 = (um.y >= thm) ? softplus_f(um.y) : 0.f;
        sp += dp0 + dp1; sm += dm0 + dm1;
        float2 o;
        o.x = fmaxf(ss.x + dp0, 0.f) - dm0;
        o.y = fmaxf(ss.y + dp1, 0.f) - dm1;
        *(float2*)(u1 + 2 * j) = o;
    }
    red[t] = sp; __syncthreads();
    for (int o = 128; o > 0; o >>= 1) { if (t < o) red[t] += red[t + o]; __syncthreads(); }
    if (t == 0) sparse_p[row] = red[0];
    __syncthreads();
    red[t] = sm; __syncthreads();
    for (int o = 128; o > 0; o >>= 1) { if (t < o) red[t] += red[t + o]; __syncthreads(); }
    if (t == 0) sparse_m[row] = red[0];
}

__global__ __launch_bounds__(256) void rownorm(
    const float* __restrict__ X, float* __restrict__ Y, int dbl)
{
    __shared__ float red[256];
    const int row = blockIdx.x, t = threadIdx.x;
    const float* x = X + (size_t)row * DIM;
    float* y = Y + (size_t)row * DIM;
    float v0 = x[t], v1 = x[t + 256], v2 = x[t + 512];
    red[t] = v0 * v0 + v1 * v1 + v2 * v2; __syncthreads();
    for (int o = 128; o > 0; o >>= 1) { if (t < o) red[t] += red[t + o]; __syncthreads(); }
    const float nrm = sqrtf(red[0]) + EPSN;
    v0 /= nrm; v1 /= nrm; v2 /= nrm;
    if (dbl) {
        __syncthreads();
        red[t] = v0 * v0 + v1 * v1 + v2 * v2; __syncthreads();
        for (int o = 128; o > 0; o >>= 1) { if (t < o) red[t] += red[t + o]; __syncthreads(); }
        const float n2 = sqrtf(red[0]) + EPSN;
        v0 /= n2; v1 /= n2; v2 /= n2;
    }
    y[t] = v0; y[t + 256] = v1; y[t + 512] = v2;
}

__global__ __launch_bounds__(256) void pos_dot(
    const float* __restrict__ zq, const float* __restrict__ zp,
    float* __restrict__ posL)
{
    __shared__ float red[256];
    const int row = blockIdx.x, t = threadIdx.x;
    const float* a = zq + (size_t)row * DIM;
    const float* b = zp + (size_t)row * DIM;
    red[t] = a[t] * b[t] + a[t + 256] * b[t + 256] + a[t + 512] * b[t + 512];
    __syncthreads();
    for (int o = 128; o > 0; o >>= 1) { if (t < o) red[t] += red[t + o]; __syncthreads(); }
    if (t == 0) posL[row] = red[0] / TEMPC;
}

// NegL holds raw dot products; scale by 1/TEMP here.
__global__ __launch_bounds__(256) void lse_loss(
    const float* __restrict__ negL, const float* __restrict__ posL,
    float* __restrict__ rowL)
{
    __shared__ float red[256];
    const int row = blockIdx.x, t = threadIdx.x;
    const float* nl = negL + (size_t)row * MNEG;
    const float p = posL[row];
    float lmax = (t == 0) ? p : -INFINITY;
    for (int j = t; j < MNEG; j += 256) lmax = fmaxf(lmax, nl[j] * INVT);
    red[t] = lmax; __syncthreads();
    for (int o = 128; o > 0; o >>= 1) { if (t < o) red[t] = fmaxf(red[t], red[t + o]); __syncthreads(); }
    const float mx = red[0];
    __syncthreads();
    float lsum = (t == 0) ? expf(p - mx) : 0.f;
    for (int j = t; j < MNEG; j += 256) lsum += expf(nl[j] * INVT - mx);
    red[t] = lsum; __syncthreads();
    for (int o = 128; o > 0; o >>= 1) { if (t < o) red[t] += red[t + o]; __syncthreads(); }
    if (t == 0) rowL[row] = mx + logf(red[0]) - p;
}

__global__ __launch_bounds__(256) void rec_row(
    const float* __restrict__ zhat, const float* __restrict__ zrn,
    float* __restrict__ part)
{
    __shared__ float red[256];
    const int row = blockIdx.x, t = threadIdx.x;
    const float* a = zhat + (size_t)row * DIM;
    const float* b = zrn + (size_t)row * DIM;
    const float d0 = a[t] - b[t], d1 = a[t + 256] - b[t + 256], d2 = a[t + 512] - b[t + 512];
    red[t] = d0 * d0 + d1 * d1 + d2 * d2;
    __syncthreads();
    for (int o = 128; o > 0; o >>= 1) { if (t < o) red[t] += red[t + o]; __syncthreads(); }
    if (t == 0) part[row] = red[0];
}

__global__ __launch_bounds__(256) void final_combine(
    const float* __restrict__ rowL, const float* __restrict__ recP,
    const float* __restrict__ spP, const float* __restrict__ spM,
    float* __restrict__ out)
{
    __shared__ float red[256];
    const int t = threadIdx.x;
    red[t] = rowL[t]; __syncthreads();
    for (int o = 128; o > 0; o >>= 1) { if (t < o) red[t] += red[t + o]; __syncthreads(); }
    const float retr = red[0] / 256.0f;
    __syncthreads();
    red[t] = recP[t]; __syncthreads();
    for (int o = 128; o > 0; o >>= 1) { if (t < o) red[t] += red[t + o]; __syncthreads(); }
    const float rec = red[0] / (float)(BATCH * DIM);
    __syncthreads();
    red[t] = spP[t] + spM[t]; __syncthreads();
    for (int o = 128; o > 0; o >>= 1) { if (t < o) red[t] += red[t + o]; __syncthreads(); }
    const float sparse = red[0] / 256.0f;
    if (t == 0) out[0] = retr + 1.0f * rec + 1e-4f * sparse;
}

extern "C" void kernel_launch(void* const* d_in, const int* in_sizes, int n_in,
                              void* d_out, int out_size, void* d_ws, size_t ws_size,
                              hipStream_t stream)
{
    const float* ht   = (const float*)d_in[0];
    const float* sr   = (const float*)d_in[1];
    const float* zpos = (const float*)d_in[2];
    const float* zneg = (const float*)d_in[3];
    const float* zr   = (const float*)d_in[4];
    const float* W1p  = (const float*)d_in[5];
    const float* b1p  = (const float*)d_in[6];
    const float* W2p  = (const float*)d_in[7];
    const float* b2p  = (const float*)d_in[8];
    const float* W1m  = (const float*)d_in[9];
    const float* b1m  = (const float*)d_in[10];
    const float* W2m  = (const float*)d_in[11];
    const float* b2m  = (const float*)d_in[12];
    const float* Wdec = (const float*)d_in[13];
    float* out = (float*)d_out;

    // workspace layout (bytes)
    char* ws = (char*)d_ws;
    float* U1   = (float*)(ws + 0);            // 31,254,528 (u_p raw -> sq); head also
                                               //   serves as gemm1 branch-m partial arena
    float* U2   = (float*)(ws + 31254528);     // 31,254,528 (u_m raw; dead after build_sq ->
                                               //   reused as decode branch-m partials)
    float* PA0  = (float*)(ws + 0);            // gemm1-m partials (33.55MB in U1+U2 region,
                                               //   free until GEMM2 writes U1/U2)
    float* P    = (float*)(ws + 62509056);     // 33,554,432 partial arena (serial reuse)
    float* Hp   = (float*)(ws + 96063488);     //      524,288
    float* Hm   = (float*)(ws + 96587776);     //      524,288
    float* Y1   = (float*)(ws + 97112064);     //      786,432
    float* Y2   = (float*)(ws + 97898496);     //      786,432
    float* Zn   = (float*)(ws + 98684928);     //   12,582,912
    float* Zp   = (float*)(ws + 111267840);    //      786,432
    float* Zrn  = (float*)(ws + 112054272);    //      786,432
    float* NegL = (float*)(ws + 112840704);    //    4,194,304
    float* tP   = (float*)(ws + 117035008);    // small vectors (256 floats each)
    float* tM   = tP + 256;
    float* spP  = tP + 512;
    float* spM  = tP + 768;
    float* posL = tP + 1024;
    float* rowL = tP + 1280;
    float* recP = tP + 1536;
    (void)in_sizes; (void)n_in; (void)out_size; (void)ws_size;

    const dim3 blk(256);

    // ---- GEMM1 dual (ht@W1p | ht@W1m), split-K 64/branch, grid 1024 (4/CU)
    //      partials: branch-p -> P (64*0.524MB = 33.55MB exact), branch-m -> ws+0
    gemm32t<0,0,0, VSZ, BOT, BOT, VSZ, 64, 2,4,128><<<dim3(2,4,128), blk, 0, stream>>>(
        ht, ht, W1p, W1m, P, PA0, nullptr, nullptr);
    reduce_bias_gelu2<<<dim3(512,2), blk, 0, stream>>>(
        P, PA0, b1p, b1m, Hp, Hm, BATCH*BOT, BOT, 64);

    // ---- GEMM2 dual (Hp@W2p | Hm@W2m), raw acc+bias epilogue, grid 956
    gemm32t<0,1,1, BOT, VSZ, VSZ, BOT, 1, 2,239,2><<<dim3(2,239,2), blk, 0, stream>>>(
        Hp, Hm, W2p, W2m, U1, U2, b2p, b2m);

    // ---- exact top-K thresholds on raw logits (both branches, one launch)
    topk_thresh2<<<dim3(2,256), dim3(TKT), 0, stream>>>(U1, U2, tP, tM);
    build_sq<<<dim3(256), blk, 0, stream>>>(U1, U2, sr, tP, tM, spP, spM);

    // ---- decode dual (sq@Wdec | sr@Wdec), split-K 32, grid 768
    //      branch-p partials -> P, branch-m partials -> dead U2 region
    gemm32t<0,0,0, VSZ, DIM, DIM, VSZ, 32, 2,6,64><<<dim3(2,6,64), blk, 0, stream>>>(
        U1, sr, Wdec, Wdec, P, U2, nullptr, nullptr);
    reduce_sum_parts<<<dim3(768), blk, 0, stream>>>(P,  Y1, BATCH*DIM, 32);
    reduce_sum_parts<<<dim3(768), blk, 0, stream>>>(U2, Y2, BATCH*DIM, 32);

    // ---- normalizations
    rownorm<<<dim3(256),  blk, 0, stream>>>(Y1, Y1, 1);   // zq (double norm)
    rownorm<<<dim3(256),  blk, 0, stream>>>(Y2, Y2, 0);   // zhat_r
    rownorm<<<dim3(4096), blk, 0, stream>>>(zneg, Zn, 0);
    rownorm<<<dim3(256),  blk, 0, stream>>>(zpos, Zp, 0);
    rownorm<<<dim3(256),  blk, 0, stream>>>(zr,   Zrn, 0);

    // ---- retrieval loss
    pos_dot<<<dim3(256), blk, 0, stream>>>(Y1, Zp, posL);
    gemm32t<1,0,0, DIM, DIM, MNEG, DIM, 4, 2,32,4><<<dim3(2,32,4), blk, 0, stream>>>(
        Y1, Y1, Zn, Zn, P, P, nullptr, nullptr);
    reduce_sum_parts<<<dim3(4096), blk, 0, stream>>>(P, NegL, BATCH*MNEG, 4);
    lse_loss<<<dim3(256), blk, 0, stream>>>(NegL, posL, rowL);

    // ---- reconstruction loss
    rec_row<<<dim3(256), blk, 0, stream>>>(Y2, Zrn, recP);

    // ---- combine
    final_combine<<<dim3(1), blk, 0, stream>>>(rowL, recP, spP, spM, out);
}

// Round 20
// 391.657 us; speedup vs baseline: 1.1342x; 1.0883x over previous
//
#include <hip/hip_runtime.h>
#include <math.h>

#define VSZ   30522
#define DIM   768
#define KDELT 768
#define BOT   512
#define BATCH 256
#define MNEG  4096
#define EPSN  1e-6f
#define TEMPC 0.05f
#define INVT  20.0f
#define TKT   1024

typedef _Float16 f16;
typedef _Float16 f16x8 __attribute__((ext_vector_type(8)));
typedef _Float16 f16x2 __attribute__((ext_vector_type(2)));
typedef float    f32x4 __attribute__((ext_vector_type(4)));

static __device__ __forceinline__ float gelu_exact(float x){
    return 0.5f * x * (1.0f + erff(x * 0.70710678118654752440f));
}
static __device__ __forceinline__ float softplus_f(float x){
    return fmaxf(x, 0.0f) + log1pf(expf(-fabsf(x)));
}
static __device__ __forceinline__ f16x2 pkh(float a, float b){
    return __builtin_bit_cast(f16x2, __builtin_amdgcn_cvt_pkrtz(a, b));
}
// order-preserving map float -> uint (handles negatives)
static __device__ __forceinline__ unsigned int fkey(float f){
    const unsigned int u = __float_as_uint(f);
    return u ^ (((unsigned int)((int)u >> 31)) | 0x80000000u);
}

// ---------------------------------------------------------------------------
// fp32-in / fp16-MFMA GEMM, 128x128 tile + XCD swizzle — EXACT R17 kernel
// (best: 410.7us). R18 (BN=64) and R19 (split-64) both failed to convert
// more resident blocks into net time (occupancy doesn't scale; extra partial
// traffic eats BW gains) — residency axis closed, split-32 restored.
// ---------------------------------------------------------------------------
template<int BSRC, int NG, int EPI, int LDA, int LDB, int N, int K, int NSPLIT,
         int GX, int GY, int GZ>
__global__ __launch_bounds__(256, 2) void gemm32t(
    const float* __restrict__ A0, const float* __restrict__ A1,
    const float* __restrict__ B0, const float* __restrict__ B1,
    float* __restrict__ C0, float* __restrict__ C1,
    const float* __restrict__ bias0, const float* __restrict__ bias1)
{
    constexpr int MN = BATCH * N;
    __shared__ f16 Al[128][40];
    __shared__ f16 Bl[128][40];
    const int t  = threadIdx.x;

    // ---- XCD-aware bijective remap (hw dispatch slot -> work id) ----
    const int flat = blockIdx.x + GX * (blockIdx.y + GY * blockIdx.z);
    constexpr int NWG = GX * GY * GZ;
    constexpr int q8 = NWG / 8, r8 = NWG % 8;
    const int xcd = flat & 7;
    const int sub = flat >> 3;
    const int wg  = (xcd < r8) ? (xcd * (q8 + 1) + sub)
                               : (r8 * (q8 + 1) + (xcd - r8) * q8 + sub);
    const int bx = wg % GX;
    const int by = (wg / GX) % GY;
    const int bz = wg / (GX * GY);

    const int m0 = bx * 128;
    const int n0 = by * 128;
    const int br = bz / NSPLIT;
    const int s  = bz % NSPLIT;
    const float* __restrict__ A = br ? A1 : A0;
    const float* __restrict__ B = br ? B1 : B0;
    float* __restrict__ C       = br ? C1 : C0;
    const float* __restrict__ bias = br ? bias1 : bias0;

    constexpr int kchunk = ((K + NSPLIT * 32 - 1) / (NSPLIT * 32)) * 32;
    const int kb = s * kchunk;
    const int ke = min(K, kb + kchunk);

    const int ar4 = t >> 2;          // staging row 0..63 (two passes)
    const int kq  = (t & 3) * 8;     // k-octet base 0,8,16,24
    const int bn  = t & 127;         // B transpose staging n
    const int bk2 = (t >> 7) * 16;   // B staging k-half base 0/16

    const int lane = t & 63, w = t >> 6;
    const int wr = (w >> 1) * 64, wc = (w & 1) * 64;
    const int fr = lane & 15, kg = (lane >> 4) * 8;

    f32x4 acc[4][4] = {};

    float4 ra[2][2];
    float  rb[16];
    float4 rb2[2][2];

    union U8 { f16x8 v; f16x2 h[4]; };

    auto loadA = [&](int k0c, int krem) {
        #pragma unroll
        for (int p = 0; p < 2; p++) {
            const float* ap = A + (size_t)(m0 + p * 64 + ar4) * LDA + k0c + kq;
            if (krem == 32) {
                ra[p][0] = *(const float4*)ap;
                ra[p][1] = *(const float4*)(ap + 4);
            } else {
                float tm[8];
                #pragma unroll
                for (int i = 0; i < 8; i++) tm[i] = (kq + i < krem) ? ap[i] : 0.f;
                ra[p][0] = make_float4(tm[0], tm[1], tm[2], tm[3]);
                ra[p][1] = make_float4(tm[4], tm[5], tm[6], tm[7]);
            }
        }
    };
    auto loadB = [&](int k0c, int krem) {
        if (BSRC == 0) {
            const bool nok = (!NG) || (n0 + bn < N);
            if (krem == 32) {
                #pragma unroll
                for (int p = 0; p < 16; p++)
                    rb[p] = nok ? B[(size_t)(k0c + bk2 + p) * LDB + n0 + bn] : 0.f;
            } else {
                #pragma unroll
                for (int p = 0; p < 16; p++) {
                    const int kk = bk2 + p;
                    rb[p] = (kk < krem && nok) ? B[(size_t)(k0c + kk) * LDB + n0 + bn] : 0.f;
                }
            }
        } else {
            #pragma unroll
            for (int p = 0; p < 2; p++) {
                const float* bp = B + (size_t)(n0 + p * 64 + ar4) * LDB + k0c + kq;
                if (krem == 32) {
                    rb2[p][0] = *(const float4*)bp;
                    rb2[p][1] = *(const float4*)(bp + 4);
                } else {
                    float tm[8];
                    #pragma unroll
                    for (int i = 0; i < 8; i++) tm[i] = (kq + i < krem) ? bp[i] : 0.f;
                    rb2[p][0] = make_float4(tm[0], tm[1], tm[2], tm[3]);
                    rb2[p][1] = make_float4(tm[4], tm[5], tm[6], tm[7]);
                }
            }
        }
    };
    auto storeA = [&]() {
        #pragma unroll
        for (int p = 0; p < 2; p++) {
            U8 u;
            u.h[0] = pkh(ra[p][0].x, ra[p][0].y);
            u.h[1] = pkh(ra[p][0].z, ra[p][0].w);
            u.h[2] = pkh(ra[p][1].x, ra[p][1].y);
            u.h[3] = pkh(ra[p][1].z, ra[p][1].w);
            *(f16x8*)&Al[p * 64 + ar4][kq] = u.v;
        }
    };
    auto storeB = [&]() {
        if (BSRC == 0) {
            U8 u0, u1;
            u0.h[0] = pkh(rb[0],  rb[1]);
            u0.h[1] = pkh(rb[2],  rb[3]);
            u0.h[2] = pkh(rb[4],  rb[5]);
            u0.h[3] = pkh(rb[6],  rb[7]);
            u1.h[0] = pkh(rb[8],  rb[9]);
            u1.h[1] = pkh(rb[10], rb[11]);
            u1.h[2] = pkh(rb[12], rb[13]);
            u1.h[3] = pkh(rb[14], rb[15]);
            *(f16x8*)&Bl[bn][bk2]     = u0.v;
            *(f16x8*)&Bl[bn][bk2 + 8] = u1.v;
        } else {
            #pragma unroll
            for (int p = 0; p < 2; p++) {
                U8 u;
                u.h[0] = pkh(rb2[p][0].x, rb2[p][0].y);
                u.h[1] = pkh(rb2[p][0].z, rb2[p][0].w);
                u.h[2] = pkh(rb2[p][1].x, rb2[p][1].y);
                u.h[3] = pkh(rb2[p][1].z, rb2[p][1].w);
                *(f16x8*)&Bl[p * 64 + ar4][kq] = u.v;
            }
        }
    };

    int k0 = kb;
    {
        const int kr = min(32, ke - k0);
        loadA(k0, kr); loadB(k0, kr);
    }
    while (k0 < ke) {
        storeA(); storeB();
        __syncthreads();
        const int k1 = k0 + 32;
        if (k1 < ke) {                       // prefetch next tile into regs
            const int kr = min(32, ke - k1);
            loadA(k1, kr); loadB(k1, kr);
        }
        f16x8 af[4], bf[4];
        #pragma unroll
        for (int m = 0; m < 4; m++) af[m] = *(const f16x8*)&Al[wr + m * 16 + fr][kg];
        #pragma unroll
        for (int n = 0; n < 4; n++) bf[n] = *(const f16x8*)&Bl[wc + n * 16 + fr][kg];
        #pragma unroll
        for (int m = 0; m < 4; m++)
            #pragma unroll
            for (int n = 0; n < 4; n++)
                acc[m][n] = __builtin_amdgcn_mfma_f32_16x16x32_f16(af[m], bf[n], acc[m][n], 0, 0, 0);
        __syncthreads();
        k0 = k1;
    }

    float* Cp = (EPI == 0) ? (C + (size_t)s * MN) : C;
    #pragma unroll
    for (int m = 0; m < 4; m++) {
        #pragma unroll
        for (int n = 0; n < 4; n++) {
            #pragma unroll
            for (int j = 0; j < 4; j++) {
                const int row = m0 + wr + m * 16 + (lane >> 4) * 4 + j;
                const int col = n0 + wc + n * 16 + fr;
                if (NG && col >= N) continue;
                if (EPI == 0) Cp[(size_t)row * N + col] = acc[m][n][j];
                else          Cp[(size_t)row * N + col] = acc[m][n][j] + bias[col];
            }
        }
    }
}

// dual-branch split-K reduce + bias + exact GELU
__global__ __launch_bounds__(256) void reduce_bias_gelu2(
    const float* __restrict__ P0, const float* __restrict__ P1,
    const float* __restrict__ bias0, const float* __restrict__ bias1,
    float* __restrict__ H0, float* __restrict__ H1,
    int MN, int N, int nsplit)
{
    const int idx = blockIdx.x * 256 + threadIdx.x;
    if (idx >= MN) return;
    const int n = idx % N;
    const float* P = blockIdx.y ? P1 : P0;
    const float* bias = blockIdx.y ? bias1 : bias0;
    float* H = blockIdx.y ? H1 : H0;
    float s = 0.f;
    for (int k = 0; k < nsplit; k++) s += P[(size_t)k * MN + idx];
    H[idx] = gelu_exact(s + bias[n]);
}

__global__ __launch_bounds__(256) void reduce_sum_parts(
    const float* __restrict__ P, float* __restrict__ Y, int MN, int nsplit)
{
    const int idx = blockIdx.x * 256 + threadIdx.x;
    if (idx >= MN) return;
    float s = 0.f;
    for (int k = 0; k < nsplit; k++) s += P[(size_t)k * MN + idx];
    Y[idx] = s;
}

// ---------------------------------------------------------------------------
// FUSED per-row kernel: (1) exact K-th-largest radix select on raw logits
// for BOTH branches (12/12/8-bit passes on order-preserving keys), keeping
// thresholds in registers; (2) build sq in place + sparse row sums — the
// row is still L2-warm from select pass 3, eliminating build_sq's separate
// 62.5MB re-read and a launch. Grid 256 rows x 1024 threads.
// ---------------------------------------------------------------------------
__global__ __launch_bounds__(TKT) void topk_build(
    float* __restrict__ U1, const float* __restrict__ U2,
    const float* __restrict__ sr,
    float* __restrict__ sparse_p, float* __restrict__ sparse_m)
{
    __shared__ unsigned int hist[4096];
    __shared__ unsigned int scan[TKT];
    __shared__ unsigned int s_pref;
    __shared__ int s_rem;
    const int row = blockIdx.x, t = threadIdx.x;
    float* fred = (float*)hist;              // build-phase reduction (aliases hist)

    float th[2];
    #pragma unroll
    for (int b = 0; b < 2; b++) {
        const float* u = (b ? U2 : U1) + (size_t)row * VSZ;
        unsigned int pref = 0;
        int remain = KDELT;
        #pragma unroll
        for (int p = 0; p < 3; p++) {
            for (int i = t; i < 4096; i += TKT) hist[i] = 0;
            __syncthreads();
            for (int j = t; j < VSZ / 2; j += TKT) {
                const float2 x = *(const float2*)(u + 2 * j);
                const unsigned int k0 = fkey(x.x);
                const unsigned int k1 = fkey(x.y);
                if (p == 0) {
                    atomicAdd(&hist[k0 >> 20], 1u);
                    atomicAdd(&hist[k1 >> 20], 1u);
                } else if (p == 1) {
                    if ((k0 >> 20) == pref) atomicAdd(&hist[(k0 >> 8) & 0xFFFu], 1u);
                    if ((k1 >> 20) == pref) atomicAdd(&hist[(k1 >> 8) & 0xFFFu], 1u);
                } else {
                    if ((k0 >> 8) == pref) atomicAdd(&hist[k0 & 0xFFu], 1u);
                    if ((k1 >> 8) == pref) atomicAdd(&hist[k1 & 0xFFu], 1u);
                }
            }
            __syncthreads();
            // suffix scan: thread t owns bins [4t, 4t+4)
            unsigned int loc = hist[4 * t] + hist[4 * t + 1] + hist[4 * t + 2] + hist[4 * t + 3];
            scan[t] = loc;
            __syncthreads();
            for (int o = 1; o < TKT; o <<= 1) {
                const unsigned int v = (t + o < TKT) ? scan[t + o] : 0u;
                __syncthreads();
                scan[t] += v;
                __syncthreads();
            }
            const unsigned int above = (t + 1 < TKT) ? scan[t + 1] : 0u;
            if (scan[t] >= (unsigned int)remain && above < (unsigned int)remain) {
                unsigned int cum = above;
                #pragma unroll
                for (int bi = 3; bi >= 0; bi--) {
                    const int bb = 4 * t + bi;
                    cum += hist[bb];
                    if (cum >= (unsigned int)remain) {
                        s_pref = (unsigned int)bb;
                        s_rem  = remain - (int)(cum - hist[bb]);
                        break;
                    }
                }
            }
            __syncthreads();
            if (p == 0)      pref = s_pref;
            else if (p == 1) pref = (pref << 12) | s_pref;
            else             pref = (pref << 8)  | s_pref;
            remain = s_rem;
            __syncthreads();
        }
        const unsigned int u2 = (pref & 0x80000000u) ? (pref ^ 0x80000000u) : ~pref;
        th[b] = __uint_as_float(u2);
    }

    // ---- build phase: U1 := clip(sr + dsp,0) - dsm; sparse sums ----
    const float thp = th[0], thm = th[1];
    float* u1 = U1 + (size_t)row * VSZ;
    const float* u2 = U2 + (size_t)row * VSZ;
    const float* s  = sr + (size_t)row * VSZ;
    float sp = 0.f, sm = 0.f;
    for (int j = t; j < VSZ / 2; j += TKT) {
        const float2 up = *(const float2*)(u1 + 2 * j);
        const float2 um = *(const float2*)(u2 + 2 * j);
        const float2 ss = *(const float2*)(s  + 2 * j);
        const float dp0 = (up.x >= thp) ? softplus_f(up.x) : 0.f;
        const float dp1 = (up.y >= thp) ? softplus_f(up.y) : 0.f;
        const float dm0 = (um.x >= thm) ? softplus_f(um.x) : 0.f;
        const float dm1 = (um.y >= thm) ? softplus_f(um.y) : 0.f;
        sp += dp0 + dp1; sm += dm0 + dm1;
        float2 o;
        o.x = fmaxf(ss.x + dp0, 0.f) - dm0;
        o.y = fmaxf(ss.y + dp1, 0.f) - dm1;
        *(float2*)(u1 + 2 * j) = o;
    }
    __syncthreads();
    fred[t] = sp; __syncthreads();
    for (int o = TKT / 2; o > 0; o >>= 1) { if (t < o) fred[t] += fred[t + o]; __syncthreads(); }
    if (t == 0) sparse_p[row] = fred[0];
    __syncthreads();
    fred[t] = sm; __syncthreads();
    for (int o = TKT / 2; o > 0; o >>= 1) { if (t < o) fred[t] += fred[t + o]; __syncthreads(); }
    if (t == 0) sparse_m[row] = fred[0];
}

__global__ __launch_bounds__(256) void rownorm(
    const float* __restrict__ X, float* __restrict__ Y, int dbl)
{
    __shared__ float red[256];
    const int row = blockIdx.x, t = threadIdx.x;
    const float* x = X + (size_t)row * DIM;
    float* y = Y + (size_t)row * DIM;
    float v0 = x[t], v1 = x[t + 256], v2 = x[t + 512];
    red[t] = v0 * v0 + v1 * v1 + v2 * v2; __syncthreads();
    for (int o = 128; o > 0; o >>= 1) { if (t < o) red[t] += red[t + o]; __syncthreads(); }
    const float nrm = sqrtf(red[0]) + EPSN;
    v0 /= nrm; v1 /= nrm; v2 /= nrm;
    if (dbl) {
        __syncthreads();
        red[t] = v0 * v0 + v1 * v1 + v2 * v2; __syncthreads();
        for (int o = 128; o > 0; o >>= 1) { if (t < o) red[t] += red[t + o]; __syncthreads(); }
        const float n2 = sqrtf(red[0]) + EPSN;
        v0 /= n2; v1 /= n2; v2 /= n2;
    }
    y[t] = v0; y[t + 256] = v1; y[t + 512] = v2;
}

__global__ __launch_bounds__(256) void pos_dot(
    const float* __restrict__ zq, const float* __restrict__ zp,
    float* __restrict__ posL)
{
    __shared__ float red[256];
    const int row = blockIdx.x, t = threadIdx.x;
    const float* a = zq + (size_t)row * DIM;
    const float* b = zp + (size_t)row * DIM;
    red[t] = a[t] * b[t] + a[t + 256] * b[t + 256] + a[t + 512] * b[t + 512];
    __syncthreads();
    for (int o = 128; o > 0; o >>= 1) { if (t < o) red[t] += red[t + o]; __syncthreads(); }
    if (t == 0) posL[row] = red[0] / TEMPC;
}

// NegL holds raw dot products; scale by 1/TEMP here.
__global__ __launch_bounds__(256) void lse_loss(
    const float* __restrict__ negL, const float* __restrict__ posL,
    float* __restrict__ rowL)
{
    __shared__ float red[256];
    const int row = blockIdx.x, t = threadIdx.x;
    const float* nl = negL + (size_t)row * MNEG;
    const float p = posL[row];
    float lmax = (t == 0) ? p : -INFINITY;
    for (int j = t; j < MNEG; j += 256) lmax = fmaxf(lmax, nl[j] * INVT);
    red[t] = lmax; __syncthreads();
    for (int o = 128; o > 0; o >>= 1) { if (t < o) red[t] = fmaxf(red[t], red[t + o]); __syncthreads(); }
    const float mx = red[0];
    __syncthreads();
    float lsum = (t == 0) ? expf(p - mx) : 0.f;
    for (int j = t; j < MNEG; j += 256) lsum += expf(nl[j] * INVT - mx);
    red[t] = lsum; __syncthreads();
    for (int o = 128; o > 0; o >>= 1) { if (t < o) red[t] += red[t + o]; __syncthreads(); }
    if (t == 0) rowL[row] = mx + logf(red[0]) - p;
}

__global__ __launch_bounds__(256) void rec_row(
    const float* __restrict__ zhat, const float* __restrict__ zrn,
    float* __restrict__ part)
{
    __shared__ float red[256];
    const int row = blockIdx.x, t = threadIdx.x;
    const float* a = zhat + (size_t)row * DIM;
    const float* b = zrn + (size_t)row * DIM;
    const float d0 = a[t] - b[t], d1 = a[t + 256] - b[t + 256], d2 = a[t + 512] - b[t + 512];
    red[t] = d0 * d0 + d1 * d1 + d2 * d2;
    __syncthreads();
    for (int o = 128; o > 0; o >>= 1) { if (t < o) red[t] += red[t + o]; __syncthreads(); }
    if (t == 0) part[row] = red[0];
}

__global__ __launch_bounds__(256) void final_combine(
    const float* __restrict__ rowL, const float* __restrict__ recP,
    const float* __restrict__ spP, const float* __restrict__ spM,
    float* __restrict__ out)
{
    __shared__ float red[256];
    const int t = threadIdx.x;
    red[t] = rowL[t]; __syncthreads();
    for (int o = 128; o > 0; o >>= 1) { if (t < o) red[t] += red[t + o]; __syncthreads(); }
    const float retr = red[0] / 256.0f;
    __syncthreads();
    red[t] = recP[t]; __syncthreads();
    for (int o = 128; o > 0; o >>= 1) { if (t < o) red[t] += red[t + o]; __syncthreads(); }
    const float rec = red[0] / (float)(BATCH * DIM);
    __syncthreads();
    red[t] = spP[t] + spM[t]; __syncthreads();
    for (int o = 128; o > 0; o >>= 1) { if (t < o) red[t] += red[t + o]; __syncthreads(); }
    const float sparse = red[0] / 256.0f;
    if (t == 0) out[0] = retr + 1.0f * rec + 1e-4f * sparse;
}

extern "C" void kernel_launch(void* const* d_in, const int* in_sizes, int n_in,
                              void* d_out, int out_size, void* d_ws, size_t ws_size,
                              hipStream_t stream)
{
    const float* ht   = (const float*)d_in[0];
    const float* sr   = (const float*)d_in[1];
    const float* zpos = (const float*)d_in[2];
    const float* zneg = (const float*)d_in[3];
    const float* zr   = (const float*)d_in[4];
    const float* W1p  = (const float*)d_in[5];
    const float* b1p  = (const float*)d_in[6];
    const float* W2p  = (const float*)d_in[7];
    const float* b2p  = (const float*)d_in[8];
    const float* W1m  = (const float*)d_in[9];
    const float* b1m  = (const float*)d_in[10];
    const float* W2m  = (const float*)d_in[11];
    const float* b2m  = (const float*)d_in[12];
    const float* Wdec = (const float*)d_in[13];
    float* out = (float*)d_out;

    // workspace layout (bytes) — R8/R17 layout
    char* ws = (char*)d_ws;
    float* U1   = (float*)(ws + 0);            // 31,254,528 (u_p raw -> sq)
    float* U2   = (float*)(ws + 31254528);     // 31,254,528 (u_m raw; dead after topk_build ->
                                               //   reused as decode branch-m partials)
    float* P    = (float*)(ws + 62509056);     // 33,554,432 partial arena (serial reuse)
    float* P1g  = (float*)(ws + 62509056 + 16777216);  // gemm1 branch-m partials
    float* Hp   = (float*)(ws + 96063488);     //      524,288
    float* Hm   = (float*)(ws + 96587776);     //      524,288
    float* Y1   = (float*)(ws + 97112064);     //      786,432
    float* Y2   = (float*)(ws + 97898496);     //      786,432
    float* Zn   = (float*)(ws + 98684928);     //   12,582,912
    float* Zp   = (float*)(ws + 111267840);    //      786,432
    float* Zrn  = (float*)(ws + 112054272);    //      786,432
    float* NegL = (float*)(ws + 112840704);    //    4,194,304
    float* tP   = (float*)(ws + 117035008);    // small vectors (256 floats each)
    float* tM   = tP + 256;
    float* spP  = tP + 512;
    float* spM  = tP + 768;
    float* posL = tP + 1024;
    float* rowL = tP + 1280;
    float* recP = tP + 1536;
    (void)in_sizes; (void)n_in; (void)out_size; (void)ws_size; (void)tM;

    const dim3 blk(256);

    // ---- GEMM1 dual (ht@W1p | ht@W1m), split-K 32 each, grid 512 blocks
    gemm32t<0,0,0, VSZ, BOT, BOT, VSZ, 32, 2,4,64><<<dim3(2,4,64), blk, 0, stream>>>(
        ht, ht, W1p, W1m, P, P1g, nullptr, nullptr);
    reduce_bias_gelu2<<<dim3(512,2), blk, 0, stream>>>(
        P, P1g, b1p, b1m, Hp, Hm, BATCH*BOT, BOT, 32);

    // ---- GEMM2 dual (Hp@W2p | Hm@W2m), raw acc+bias epilogue, grid 956
    gemm32t<0,1,1, BOT, VSZ, VSZ, BOT, 1, 2,239,2><<<dim3(2,239,2), blk, 0, stream>>>(
        Hp, Hm, W2p, W2m, U1, U2, b2p, b2m);

    // ---- fused top-K (both branches) + sq build + sparse sums
    topk_build<<<dim3(256), dim3(TKT), 0, stream>>>(U1, U2, sr, spP, spM);

    // ---- decode dual (sq@Wdec | sr@Wdec), split-K 32, grid 768
    //      branch-p partials -> P, branch-m partials -> dead U2 region
    gemm32t<0,0,0, VSZ, DIM, DIM, VSZ, 32, 2,6,64><<<dim3(2,6,64), blk, 0, stream>>>(
        U1, sr, Wdec, Wdec, P, U2, nullptr, nullptr);
    reduce_sum_parts<<<dim3(768), blk, 0, stream>>>(P,  Y1, BATCH*DIM, 32);
    reduce_sum_parts<<<dim3(768), blk, 0, stream>>>(U2, Y2, BATCH*DIM, 32);

    // ---- normalizations
    rownorm<<<dim3(256),  blk, 0, stream>>>(Y1, Y1, 1);   // zq (double norm)
    rownorm<<<dim3(256),  blk, 0, stream>>>(Y2, Y2, 0);   // zhat_r
    rownorm<<<dim3(4096), blk, 0, stream>>>(zneg, Zn, 0);
    rownorm<<<dim3(256),  blk, 0, stream>>>(zpos, Zp, 0);
    rownorm<<<dim3(256),  blk, 0, stream>>>(zr,   Zrn, 0);

    // ---- retrieval loss
    pos_dot<<<dim3(256), blk, 0, stream>>>(Y1, Zp, posL);
    gemm32t<1,0,0, DIM, DIM, MNEG, DIM, 4, 2,32,4><<<dim3(2,32,4), blk, 0, stream>>>(
        Y1, Y1, Zn, Zn, P, P, nullptr, nullptr);
    reduce_sum_parts<<<dim3(4096), blk, 0, stream>>>(P, NegL, BATCH*MNEG, 4);
    lse_loss<<<dim3(256), blk, 0, stream>>>(NegL, posL, rowL);

    // ---- reconstruction loss
    rec_row<<<dim3(256), blk, 0, stream>>>(Y2, Zrn, recP);

    // ---- combine
    final_combine<<<dim3(1), blk, 0, stream>>>(rowL, recP, spP, spM, out);
}